// Round 4
// baseline (269.941 us; speedup 1.0000x reference)
//
#include <hip/hip_runtime.h>
#include <math.h>

#define NQ 12
#define NL 6
#define BATCHN 8192
#define DIN 512

// ============================================================================
// Virtual-relabel scheme: CNOT chain new[d]=old[sig(d)], sig(d)=d^(d<<1) is
// linear over GF(2)^12. Data never moves for CNOTs; instead layer-l RY on
// logical wire w pairs storage indices differing by M = Phi(sig^l(e_w)), with
// sign bit parity(p & S), S = Phi((sig^T)^(16-l)(e_w)).  sig^16 = I.
// Storage: bit 0-5 = lane, 6-11 = reg.  Phi chosen so only wires 0,1 per
// layer need DS ops (lane bit5 -> bperm, bit4 -> swizzle); lane bits 0,1
// (quad_perm), 3 (row_ror:8) cost 1 VALU, bit 2 costs 3 (shl4/shr4+sel).
// ============================================================================

constexpr int PHI[12] = {5, 4, 2, 3, 1, 0, 6, 7, 8, 9, 10, 11};

constexpr int sig_(int x)  { return (x ^ (x << 1)) & 0xFFF; }
constexpr int sigT_(int x) { return (x ^ (x >> 1)) & 0xFFF; }
constexpr int sigpow(int k, int x)  { while (k--) x = sig_(x);  return x; }
constexpr int sigTpow(int k, int x) { while (k--) x = sigT_(x); return x; }
constexpr int phimap(int m) {
  int r = 0;
  for (int w = 0; w < 12; ++w) if ((m >> w) & 1) r |= 1 << PHI[w];
  return r;
}
constexpr int MASK(int l, int w)  { return phimap(sigpow(l, 1 << w)); }
constexpr int SMASK(int l, int w) { return phimap(sigTpow(16 - l, 1 << w)); }
constexpr int ZMASK(int w)        { return phimap(sigTpow(16 - NL, 1 << w)); }
constexpr int topbit(int m) { int b = 0; for (int i = 0; i < 12; ++i) if ((m >> i) & 1) b = i; return 1 << b; }
constexpr int par_(int x) { return __builtin_popcount(x) & 1; }

// ---- cross-lane primitives ------------------------------------------------
template <int CTRL>
__device__ __forceinline__ float dppf(float v) {
  return __int_as_float(__builtin_amdgcn_mov_dpp(__float_as_int(v), CTRL, 0xF, 0xF, true));
}
template <int PAT>
__device__ __forceinline__ float swzf(float v) {
  return __int_as_float(__builtin_amdgcn_ds_swizzle(__float_as_int(v), PAT));
}
__device__ __forceinline__ float bperm(int addr, float v) {
  return __int_as_float(__builtin_amdgcn_ds_bpermute(addr, __float_as_int(v)));
}

// partner fetch: value of st at lane^M (M = 1..63, compile time)
template <int M>
__device__ __forceinline__ float xlane(float v, int lane, int lane4x) {
  static_assert(M >= 1 && M < 64, "");
  if constexpr (M & 32) {
    return bperm(lane4x ^ (M << 2), v);          // 1 VALU + 1 DS
  } else if constexpr (M & 16) {
    return swzf<(M << 10) | 0x1F>(v);            // 1 DS (xor over bits 0-4)
  } else {
    float r = v;
    if constexpr ((M & 3) == 1) r = dppf<0xB1>(r);        // quad_perm [1,0,3,2]
    else if constexpr ((M & 3) == 2) r = dppf<0x4E>(r);   // quad_perm [2,3,0,1]
    else if constexpr ((M & 3) == 3) r = dppf<0x1B>(r);   // quad_perm [3,2,1,0]
    if constexpr (M & 8) r = dppf<0x128>(r);              // row_ror:8 == xor 8
    if constexpr (M & 4) {                                // xor 4: shl4/shr4 + sel
      float a = dppf<0x104>(r);                           // row_shl:4
      float b = dppf<0x114>(r);                           // row_shr:4
      r = (lane & 4) ? b : a;
    }
    return r;
  }
}

__device__ __forceinline__ float wave_sum(float v) {
  v += dppf<0xB1>(v);
  v += dppf<0x4E>(v);
  v += swzf<0x101F>(v);
  v += dppf<0x128>(v);
  v += swzf<0x401F>(v);
  v += __shfl_xor(v, 32, 64);
  return v;
}

// ---- one RY (tan form): st[p] += ts_eff(p) * st[p ^ M] --------------------
template <int M, int S>
__device__ __forceinline__ void apply_wire(float (&st)[64], float t, int lane, int lane4x) {
  constexpr int Mreg = (M >> 6) & 63, Mlane = M & 63;
  constexpr int Sreg = (S >> 6) & 63, Slane = S & 63;
  const float ts = (__popc(lane & Slane) & 1) ? t : -t;

  if constexpr (Mreg == 0) {
    #pragma unroll
    for (int r = 0; r < 64; ++r) {
      const float p = xlane<Mlane>(st[r], lane, lane4x);
      st[r] = fmaf((par_(r & Sreg) ? -ts : ts), p, st[r]);
    }
  } else {
    constexpr int hb = topbit(Mreg);
    constexpr bool flip2 = par_(Mreg & Sreg);  // ts_eff(r2) = flip2 ? -ts_eff(r) : ts_eff(r)
    #pragma unroll
    for (int r = 0; r < 64; ++r) {
      if (r & hb) continue;
      const int r2 = r ^ Mreg;
      const float t0 = par_(r & Sreg) ? -ts : ts;
      const float t2 = flip2 ? -t0 : t0;
      if constexpr (Mlane == 0) {
        const float a0 = st[r], a1 = st[r2];
        st[r]  = fmaf(t0, a1, a0);
        st[r2] = fmaf(t2, a0, a1);
      } else {
        const float pa = xlane<Mlane>(st[r2], lane, lane4x);
        const float pb = xlane<Mlane>(st[r],  lane, lane4x);
        st[r]  = fmaf(t0, pa, st[r]);
        st[r2] = fmaf(t2, pb, st[r2]);
      }
    }
  }
}

template <int L>
__device__ __forceinline__ void do_layer(float (&st)[64], const float* wt, int lane, int lane4x) {
  const float* tw = wt + L * NQ;
  apply_wire<MASK(L, 0),  SMASK(L, 0)>(st, tw[0],  lane, lane4x);
  apply_wire<MASK(L, 1),  SMASK(L, 1)>(st, tw[1],  lane, lane4x);
  apply_wire<MASK(L, 2),  SMASK(L, 2)>(st, tw[2],  lane, lane4x);
  apply_wire<MASK(L, 3),  SMASK(L, 3)>(st, tw[3],  lane, lane4x);
  apply_wire<MASK(L, 4),  SMASK(L, 4)>(st, tw[4],  lane, lane4x);
  apply_wire<MASK(L, 5),  SMASK(L, 5)>(st, tw[5],  lane, lane4x);
  apply_wire<MASK(L, 6),  SMASK(L, 6)>(st, tw[6],  lane, lane4x);
  apply_wire<MASK(L, 7),  SMASK(L, 7)>(st, tw[7],  lane, lane4x);
  apply_wire<MASK(L, 8),  SMASK(L, 8)>(st, tw[8],  lane, lane4x);
  apply_wire<MASK(L, 9),  SMASK(L, 9)>(st, tw[9],  lane, lane4x);
  apply_wire<MASK(L, 10), SMASK(L, 10)>(st, tw[10], lane, lane4x);
  apply_wire<MASK(L, 11), SMASK(L, 11)>(st, tw[11], lane, lane4x);
}

template <int W>
__device__ __forceinline__ float zpart(const float (&sq)[64], float tot, int lane) {
  constexpr int Z = ZMASK(W);
  constexpr int Zreg = (Z >> 6) & 63, Zlane = Z & 63;
  float s;
  if constexpr (Zreg != 0) {
    float neg = 0.f;
    #pragma unroll
    for (int r = 0; r < 64; ++r)
      if (par_(r & Zreg)) neg += sq[r];
    s = fmaf(-2.f, neg, tot);
  } else {
    s = tot;
  }
  if constexpr (Zlane != 0)
    return (__popc(lane & Zlane) & 1) ? -s : s;
  else
    return s;
}

// One wave per batch element; st[64] in arch VGPRs (waves_per_eu(2,2) ->
// 256-reg budget so the allocator has no reason to shunt st into AGPRs;
// R1/R2 showed 128-budget splits 64 arch + 64 acc -> ~2x VALU churn).
__global__ void __launch_bounds__(256)
__attribute__((amdgpu_waves_per_eu(2, 2)))
dqc_kernel(const float* __restrict__ x,
           const float* __restrict__ pre_w,
           const float* __restrict__ pre_b,
           const float* __restrict__ weights,
           const float* __restrict__ post_w,
           const float* __restrict__ post_b,
           float* __restrict__ out)
{
  const int lane   = threadIdx.x & 63;
  const int wid    = threadIdx.x >> 6;
  const int b      = blockIdx.x * 4 + wid;
  const int lane4x = lane << 2;

  __shared__ float wt[NL * NQ];
  if (threadIdx.x < NL * NQ)
    wt[threadIdx.x] = tanf(0.5f * weights[threadIdx.x]);
  __syncthreads();

  // ---- pre-GEMM: pre[w] = x[b,:] . pre_w[w,:]
  float acc[NQ];
  const float* xr = x + (size_t)b * DIN + lane * 8;
  const float4 xa = *(const float4*)(xr);
  const float4 xb = *(const float4*)(xr + 4);
  #pragma unroll
  for (int w = 0; w < NQ; ++w) {
    const float* wr = pre_w + w * DIN + lane * 8;
    const float4 wa = *(const float4*)(wr);
    const float4 wb = *(const float4*)(wr + 4);
    acc[w] = xa.x * wa.x + xa.y * wa.y + xa.z * wa.z + xa.w * wa.w
           + xb.x * wb.x + xb.y * wb.y + xb.z * wb.z + xb.w * wb.w;
  }
  #pragma unroll
  for (int w = 0; w < NQ; ++w) acc[w] = wave_sum(acc[w]);

  // ---- initial per-qubit vectors
  const float PI_4 = 0.78539816339744830962f;
  const float INV_SQRT2 = 0.70710678118654752440f;
  float v0[NQ], v1[NQ];
  #pragma unroll
  for (int w = 0; w < NQ; ++w) {
    float h = (acc[w] + pre_b[w]) * PI_4;
    float s, c;
    sincosf(h, &s, &c);
    v0[w] = (c - s) * INV_SQRT2;
    v1[w] = (c + s) * INV_SQRT2;
  }

  // ---- initial product state, PHI layout:
  // wire0<->lane bit5, 1<->4, 2<->2, 3<->3, 4<->1, 5<->0; wires 6-11 <-> reg bits 0-5
  float lp = (((lane >> 5) & 1) ? v1[0] : v0[0])
           * (((lane >> 4) & 1) ? v1[1] : v0[1])
           * (((lane >> 2) & 1) ? v1[2] : v0[2])
           * (((lane >> 3) & 1) ? v1[3] : v0[3])
           * (((lane >> 1) & 1) ? v1[4] : v0[4])
           * (((lane >> 0) & 1) ? v1[5] : v0[5]);

  float st[64];
  #pragma unroll
  for (int r = 0; r < 64; ++r) {
    float p = lp;
    #pragma unroll
    for (int j = 0; j < 6; ++j) p *= ((r >> j) & 1) ? v1[6 + j] : v0[6 + j];
    st[r] = p;
  }

  // ---- 6 layers (12 RYs each; CNOT chains are absorbed into the masks)
  do_layer<0>(st, wt, lane, lane4x);
  do_layer<1>(st, wt, lane, lane4x);
  do_layer<2>(st, wt, lane, lane4x);
  do_layer<3>(st, wt, lane, lane4x);
  do_layer<4>(st, wt, lane, lane4x);
  do_layer<5>(st, wt, lane, lane4x);

  // ---- measurement (scale-invariant: normalize by total at the end)
  #pragma unroll
  for (int r = 0; r < 64; ++r) st[r] *= st[r];

  float tot = 0.f;
  #pragma unroll
  for (int r = 0; r < 64; ++r) tot += st[r];

  float z[NQ];
  z[0]  = zpart<0>(st, tot, lane);
  z[1]  = zpart<1>(st, tot, lane);
  z[2]  = zpart<2>(st, tot, lane);
  z[3]  = zpart<3>(st, tot, lane);
  z[4]  = zpart<4>(st, tot, lane);
  z[5]  = zpart<5>(st, tot, lane);
  z[6]  = zpart<6>(st, tot, lane);
  z[7]  = zpart<7>(st, tot, lane);
  z[8]  = zpart<8>(st, tot, lane);
  z[9]  = zpart<9>(st, tot, lane);
  z[10] = zpart<10>(st, tot, lane);
  z[11] = zpart<11>(st, tot, lane);

  const float tot_s = wave_sum(tot);
  #pragma unroll
  for (int w = 0; w < NQ; ++w) z[w] = wave_sum(z[w]);

  if (lane == 0) {
    const float inv = 1.0f / tot_s;
    float o = post_b[0];
    #pragma unroll
    for (int w = 0; w < NQ; ++w) o = fmaf(z[w] * inv, post_w[w], o);
    out[b] = o;
  }
}

extern "C" void kernel_launch(void* const* d_in, const int* in_sizes, int n_in,
                              void* d_out, int out_size, void* d_ws, size_t ws_size,
                              hipStream_t stream) {
  (void)in_sizes; (void)n_in; (void)out_size; (void)d_ws; (void)ws_size;
  const float* x       = (const float*)d_in[0];
  const float* pre_w   = (const float*)d_in[1];
  const float* pre_b   = (const float*)d_in[2];
  const float* weights = (const float*)d_in[3];
  const float* post_w  = (const float*)d_in[4];
  const float* post_b  = (const float*)d_in[5];
  float* out = (float*)d_out;

  dqc_kernel<<<BATCHN / 4, 256, 0, stream>>>(x, pre_w, pre_b, weights,
                                             post_w, post_b, out);
}

// Round 6
// 142.337 us; speedup vs baseline: 1.8965x; 1.8965x over previous
//
#include <hip/hip_runtime.h>
#include <math.h>

#define NQ 12
#define NL 6
#define BATCHN 8192
#define DIN 512

typedef _Float16 f16;
typedef __attribute__((ext_vector_type(8)))  _Float16 f16x8;
typedef __attribute__((ext_vector_type(16))) float    f32x16;
typedef unsigned int u32;
typedef __attribute__((ext_vector_type(4))) u32 u32x4;

// ============================================================================
// 12-matmul formulation. State = 64x64 (P-factor: wires 0-5, Q-factor: wires
// 6-11). MFMA contracts the reg-resident factor and swaps residency, so
// alternating matmuls apply Kron(6 RYs) to each factor. CNOT chain
// sigma(d)=d^(d<<1) factors as sigmaP (x) sigmaQ (x) condflip(wire5->wire6):
// sigmaP/sigmaQ are folded into the NEXT matmul's matrix (W[a][c]=R[a][F6(c)],
// F6 = prefix-xor = sigma^-1); the cond-flip (conditioned on parity(p&63) in
// the stored pre-sigma frame) is an explicit lane-xor-1 exchange via DPP.
// Matrices are weight-only: computed per call by setup_mats into d_ws in
// exact B-fragment order.
//   MFMA 32x32x16 f16 layouts (m74/m101-verified D; A/B per CDNA pattern):
//   A[m][k]: m=lane&31, k=8*(lane>>5)+i ; B[k][n]: n=lane&31, k=8*(lane>>5)+i
//   D[m][n]: n=lane&31, m=(reg&3)+8*(reg>>2)+4*(lane>>5), tiles d[mt][nt].
// ============================================================================

__device__ __forceinline__ u32 pkrtz(float a, float b) {
  auto p = __builtin_amdgcn_cvt_pkrtz(a, b);   // __fp16 ext_vector(2)
  return __builtin_bit_cast(u32, p);
}
__device__ __forceinline__ u32 bperm(int addr, u32 v) {
  return (u32)__builtin_amdgcn_ds_bpermute(addr, (int)v);
}
__device__ __forceinline__ float dppx1(float v) {  // lane xor 1 (quad_perm)
  return __int_as_float(__builtin_amdgcn_mov_dpp(__float_as_int(v), 0xB1, 0xF, 0xF, true));
}
__device__ __forceinline__ float dppx2(float v) {
  return __int_as_float(__builtin_amdgcn_mov_dpp(__float_as_int(v), 0x4E, 0xF, 0xF, true));
}
__device__ __forceinline__ float dppx8(float v) {  // row_ror:8 == xor 8
  return __int_as_float(__builtin_amdgcn_mov_dpp(__float_as_int(v), 0x128, 0xF, 0xF, true));
}
template <int PAT>
__device__ __forceinline__ float swzf(float v) {
  return __int_as_float(__builtin_amdgcn_ds_swizzle(__float_as_int(v), PAT));
}
__device__ __forceinline__ float wave_sum(float v) {
  v += dppx1(v);
  v += dppx2(v);
  v += swzf<0x101F>(v);   // xor 4
  v += dppx8(v);
  v += swzf<0x401F>(v);   // xor 16
  v += __shfl_xor(v, 32, 64);
  return v;
}
__device__ __forceinline__ f16x8 asf(const u32 a[4]) {
  u32x4 v; v.x = a[0]; v.y = a[1]; v.z = a[2]; v.w = a[3];
  return __builtin_bit_cast(f16x8, v);
}
__device__ __forceinline__ f16x8 ldB(const u32* __restrict__ p, int off) {
  u32x4 v = *(const u32x4*)(p + off);
  return __builtin_bit_cast(f16x8, v);
}

// ---------- setup: 12 matrices (fp16, B-fragment order) from weights --------
__global__ void setup_mats(const float* __restrict__ weights, u32* __restrict__ Bbuf) {
  const int mm = blockIdx.x;    // 0..11 ; layer = mm>>1, side: 0=P(w0-5),1=Q(w6-11)
  const int l  = mm >> 1;
  const int qs = mm & 1;
  __shared__ float c6[6], s6[6];
  if (threadIdx.x < 6) {
    float h = 0.5f * weights[l * NQ + qs * 6 + threadIdx.x];
    c6[threadIdx.x] = cosf(h);
    s6[threadIdx.x] = sinf(h);
  }
  __syncthreads();
  for (int t = threadIdx.x; t < 2048; t += 256) {
    const int lane = (t >> 2) & 63;
    const int fk   = t >> 8;          // nt*4 + kt
    const int kt   = fk & 3;
    const int nt   = fk >> 2;
    const int n     = nt * 32 + (lane & 31);
    const int kbase = kt * 16 + (lane >> 5) * 8 + (t & 3) * 2;
    float v[2];
    #pragma unroll
    for (int u = 0; u < 2; ++u) {
      int k = kbase + u;
      int bb = k;
      if (l >= 1) { bb ^= bb << 1; bb ^= bb << 2; bb ^= bb << 4; bb &= 63; } // F6 = prefix-xor
      float prod = 1.f;
      #pragma unroll
      for (int w = 0; w < 6; ++w) {
        const int aw = (n >> w) & 1, bw = (bb >> w) & 1;
        prod *= (aw == bw) ? c6[w] : (aw ? s6[w] : -s6[w]);  // RY: [[c,-s],[s,c]]
      }
      v[u] = prod;
    }
    Bbuf[mm * 2048 + t] = pkrtz(v[0], v[1]);
  }
}

// ---------- one matmul step: repack prev D -> A frags, 16 MFMA --------------
__device__ __forceinline__ void mm_step(f32x16 (&d)[2][2], const u32* __restrict__ Bl,
                                        bool hi, int axor) {
  u32 fr[2][4][4];
  #pragma unroll
  for (int kt = 0; kt < 4; ++kt) {
    const int s  = kt >> 1;
    const int b0 = 4 * ((2 * kt) & 3);
    const int b1 = 4 * ((2 * kt + 1) & 3);
    #pragma unroll
    for (int mt = 0; mt < 2; ++mt) {
      u32 p0a = pkrtz(d[s][mt][b0 + 0], d[s][mt][b0 + 1]);
      u32 p0b = pkrtz(d[s][mt][b0 + 2], d[s][mt][b0 + 3]);
      u32 p1a = pkrtz(d[s][mt][b1 + 0], d[s][mt][b1 + 1]);
      u32 p1b = pkrtz(d[s][mt][b1 + 2], d[s][mt][b1 + 3]);
      u32 x0a = bperm(axor, p0a), x0b = bperm(axor, p0b);
      u32 x1a = bperm(axor, p1a), x1b = bperm(axor, p1b);
      fr[mt][kt][0] = hi ? x1a : p0a;
      fr[mt][kt][1] = hi ? x1b : p0b;
      fr[mt][kt][2] = hi ? p1a : x0a;
      fr[mt][kt][3] = hi ? p1b : x0b;
    }
  }
  f32x16 nd[2][2];
  #pragma unroll
  for (int kt = 0; kt < 4; ++kt) {
    f16x8 A0 = asf(fr[0][kt]);
    f16x8 A1 = asf(fr[1][kt]);
    f16x8 B0 = ldB(Bl, (0 * 4 + kt) * 256);
    f16x8 B1 = ldB(Bl, (1 * 4 + kt) * 256);
    if (kt == 0) {
      f32x16 z{};
      nd[0][0] = __builtin_amdgcn_mfma_f32_32x32x16_f16(A0, B0, z, 0, 0, 0);
      nd[0][1] = __builtin_amdgcn_mfma_f32_32x32x16_f16(A0, B1, z, 0, 0, 0);
      nd[1][0] = __builtin_amdgcn_mfma_f32_32x32x16_f16(A1, B0, z, 0, 0, 0);
      nd[1][1] = __builtin_amdgcn_mfma_f32_32x32x16_f16(A1, B1, z, 0, 0, 0);
    } else {
      nd[0][0] = __builtin_amdgcn_mfma_f32_32x32x16_f16(A0, B0, nd[0][0], 0, 0, 0);
      nd[0][1] = __builtin_amdgcn_mfma_f32_32x32x16_f16(A0, B1, nd[0][1], 0, 0, 0);
      nd[1][0] = __builtin_amdgcn_mfma_f32_32x32x16_f16(A1, B0, nd[1][0], 0, 0, 0);
      nd[1][1] = __builtin_amdgcn_mfma_f32_32x32x16_f16(A1, B1, nd[1][1], 0, 0, 0);
    }
  }
  d[0][0] = nd[0][0]; d[0][1] = nd[0][1];
  d[1][0] = nd[1][0]; d[1][1] = nd[1][1];
}

// ---------- cond-flip: wire5 (P) controls wire6 (Q) lane-xor-1 --------------
// State after even MM: m=p (regs+l5), n=q' (lanes). Condition parity(p&63):
// p = (r&3) + 8*(r>>2) + 4*l5 + 32*mt -> per-reg constexpr parity ^ l5.
__device__ __forceinline__ void flip_step(f32x16 (&d)[2][2], bool hi) {
  #pragma unroll
  for (int mt = 0; mt < 2; ++mt)
    #pragma unroll
    for (int nt = 0; nt < 2; ++nt)
      #pragma unroll
      for (int r = 0; r < 16; ++r) {
        const int par0 = (__builtin_popcount(r & 3) + __builtin_popcount(r >> 2) + mt) & 1;
        float cur = d[mt][nt][r];
        float partner = dppx1(cur);
        const bool cond = par0 ? !hi : hi;
        d[mt][nt][r] = cond ? partner : cur;
      }
}

__global__ void __launch_bounds__(256) __attribute__((amdgpu_waves_per_eu(3, 3)))
dqc_main(const float* __restrict__ x,
         const float* __restrict__ pre_w,
         const float* __restrict__ pre_b,
         const float* __restrict__ post_w,
         const float* __restrict__ post_b,
         const u32* __restrict__ Bbuf,
         float* __restrict__ out)
{
  const int lane = threadIdx.x & 63;
  const bool hi  = lane >= 32;
  const int b    = blockIdx.x * 4 + (threadIdx.x >> 6);
  const int axor = (lane ^ 32) << 2;

  // ---- pre-GEMM: pre[w] = x[b,:] . pre_w[w,:]
  float acc[NQ];
  const float* xr = x + (size_t)b * DIN + lane * 8;
  const float4 xa = *(const float4*)(xr);
  const float4 xb = *(const float4*)(xr + 4);
  #pragma unroll
  for (int w = 0; w < NQ; ++w) {
    const float* wr = pre_w + w * DIN + lane * 8;
    const float4 wa = *(const float4*)(wr);
    const float4 wb = *(const float4*)(wr + 4);
    acc[w] = xa.x * wa.x + xa.y * wa.y + xa.z * wa.z + xa.w * wa.w
           + xb.x * wb.x + xb.y * wb.y + xb.z * wb.z + xb.w * wb.w;
  }
  #pragma unroll
  for (int w = 0; w < NQ; ++w) acc[w] = wave_sum(acc[w]);

  const float PI_4 = 0.78539816339744830962f;
  const float INV_SQRT2 = 0.70710678118654752440f;
  float v0[NQ], v1[NQ];
  #pragma unroll
  for (int w = 0; w < NQ; ++w) {
    float h = (acc[w] + pre_b[w]) * PI_4;
    float s, c;
    sincosf(h, &s, &c);
    v0[w] = (c - s) * INV_SQRT2;
    v1[w] = (c + s) * INV_SQRT2;
  }

  // ---- initial product state, built directly as MM0 A-frags:
  // A[m=q][k=p], q = 32*mt + (lane&31), p = 16*kt + 8*hi + j
  float base8[8];
  #pragma unroll
  for (int j = 0; j < 8; ++j)
    base8[j] = ((j & 1) ? v1[0] : v0[0]) * ((j & 2) ? v1[1] : v0[1]) * ((j & 4) ? v1[2] : v0[2]);
  float hiP[4];
  #pragma unroll
  for (int kt = 0; kt < 4; ++kt)
    hiP[kt] = (hi ? v1[3] : v0[3]) * ((kt & 1) ? v1[4] : v0[4]) * ((kt & 2) ? v1[5] : v0[5]);
  const float qb = ((lane & 1) ? v1[6] : v0[6]) * ((lane & 2) ? v1[7] : v0[7])
                 * ((lane & 4) ? v1[8] : v0[8]) * ((lane & 8) ? v1[9] : v0[9])
                 * ((lane & 16) ? v1[10] : v0[10]);
  const float qm0 = qb * v0[11], qm1 = qb * v1[11];

  f32x16 d[2][2];
  {
    const u32* Bl = Bbuf + lane * 4;   // mm = 0
    #pragma unroll
    for (int kt = 0; kt < 4; ++kt) {
      u32 a0[4], a1[4];
      #pragma unroll
      for (int dw = 0; dw < 4; ++dw) {
        const float e0 = base8[2 * dw] * hiP[kt];
        const float e1 = base8[2 * dw + 1] * hiP[kt];
        a0[dw] = pkrtz(qm0 * e0, qm0 * e1);
        a1[dw] = pkrtz(qm1 * e0, qm1 * e1);
      }
      f16x8 A0 = asf(a0), A1 = asf(a1);
      f16x8 B0 = ldB(Bl, (0 * 4 + kt) * 256);
      f16x8 B1 = ldB(Bl, (1 * 4 + kt) * 256);
      if (kt == 0) {
        f32x16 z{};
        d[0][0] = __builtin_amdgcn_mfma_f32_32x32x16_f16(A0, B0, z, 0, 0, 0);
        d[0][1] = __builtin_amdgcn_mfma_f32_32x32x16_f16(A0, B1, z, 0, 0, 0);
        d[1][0] = __builtin_amdgcn_mfma_f32_32x32x16_f16(A1, B0, z, 0, 0, 0);
        d[1][1] = __builtin_amdgcn_mfma_f32_32x32x16_f16(A1, B1, z, 0, 0, 0);
      } else {
        d[0][0] = __builtin_amdgcn_mfma_f32_32x32x16_f16(A0, B0, d[0][0], 0, 0, 0);
        d[0][1] = __builtin_amdgcn_mfma_f32_32x32x16_f16(A0, B1, d[0][1], 0, 0, 0);
        d[1][0] = __builtin_amdgcn_mfma_f32_32x32x16_f16(A1, B0, d[1][0], 0, 0, 0);
        d[1][1] = __builtin_amdgcn_mfma_f32_32x32x16_f16(A1, B1, d[1][1], 0, 0, 0);
      }
    }
  }

  // ---- MM 1..11, cond-flip after each odd (Q-side) matmul
  #pragma unroll
  for (int t = 1; t < 12; ++t) {
    mm_step(d, Bbuf + t * 2048 + lane * 4, hi, axor);
    if (t & 1) flip_step(d, hi);
  }

  // ---- measurement (state: m=p, n=q', both in pre-sigma frames ->
  //      true bit w = prefix-parity of stored bits 0..w)
  float tot = 0.f, s0 = 0.f;
  float zp0 = 0.f, zp1 = 0.f, zp3 = 0.f, zp4 = 0.f, zp5 = 0.f;
  #pragma unroll
  for (int mt = 0; mt < 2; ++mt)
    #pragma unroll
    for (int nt = 0; nt < 2; ++nt)
      #pragma unroll
      for (int r = 0; r < 16; ++r) {
        float v = d[mt][nt][r];
        float sq = v * v;
        tot += sq;
        if (nt == 0) s0 += sq;
        const int c0 = r & 1;
        const int c1 = (r ^ (r >> 1)) & 1;
        const int c3 = c1 ^ ((r >> 2) & 1);
        const int c4 = c3 ^ ((r >> 3) & 1);
        const int c5 = c4 ^ mt;
        zp0 += c0 ? -sq : sq;
        zp1 += c1 ? -sq : sq;
        zp3 += c3 ? -sq : sq;
        zp4 += c4 ? -sq : sq;
        zp5 += c5 ? -sq : sq;
      }
  const float sgnhi = hi ? -1.f : 1.f;   // p2 = l5 enters wires >= 2
  float z[12];
  z[0] = zp0;
  z[1] = zp1;
  z[2] = sgnhi * zp1;   // reg-part of wire2 mask == wire1 mask
  z[3] = sgnhi * zp3;
  z[4] = sgnhi * zp4;
  z[5] = sgnhi * zp5;
  #pragma unroll
  for (int j = 0; j < 5; ++j) {
    const int par = __builtin_popcount(lane & ((2 << j) - 1)) & 1;
    z[6 + j] = par ? -tot : tot;
  }
  {
    const int par = __builtin_popcount(lane & 31) & 1;  // q'5 = nt handled via s0
    z[11] = (par ? -1.f : 1.f) * (2.f * s0 - tot);
  }
  const float tots = wave_sum(tot);
  #pragma unroll
  for (int w = 0; w < 12; ++w) z[w] = wave_sum(z[w]);

  if (lane == 0) {
    const float inv = 1.0f / tots;
    float o = post_b[0];
    #pragma unroll
    for (int w = 0; w < 12; ++w) o = fmaf(z[w] * inv, post_w[w], o);
    out[b] = o;
  }
}

extern "C" void kernel_launch(void* const* d_in, const int* in_sizes, int n_in,
                              void* d_out, int out_size, void* d_ws, size_t ws_size,
                              hipStream_t stream) {
  (void)in_sizes; (void)n_in; (void)out_size; (void)ws_size;
  const float* x       = (const float*)d_in[0];
  const float* pre_w   = (const float*)d_in[1];
  const float* pre_b   = (const float*)d_in[2];
  const float* weights = (const float*)d_in[3];
  const float* post_w  = (const float*)d_in[4];
  const float* post_b  = (const float*)d_in[5];
  float* out = (float*)d_out;
  u32* Bbuf = (u32*)d_ws;   // 12 * 2048 dwords = 96 KiB

  setup_mats<<<12, 256, 0, stream>>>(weights, Bbuf);
  dqc_main<<<BATCHN / 4, 256, 0, stream>>>(x, pre_w, pre_b, post_w, post_b, Bbuf, out);
}

// Round 7
// 138.282 us; speedup vs baseline: 1.9521x; 1.0293x over previous
//
#include <hip/hip_runtime.h>
#include <math.h>

#define NQ 12
#define NL 6
#define BATCHN 8192
#define DIN 512

typedef _Float16 f16;
typedef __attribute__((ext_vector_type(8)))  _Float16 f16x8;
typedef __attribute__((ext_vector_type(16))) float    f32x16;
typedef unsigned int u32;
typedef __attribute__((ext_vector_type(4))) u32 u32x4;

// ============================================================================
// 12-matmul formulation. State = 64x64 (P-factor: wires 0-5, Q-factor: wires
// 6-11). MFMA contracts the reg-resident factor and swaps residency, so
// alternating matmuls apply Kron(6 RYs) to each factor. CNOT chain
// sigma(d)=d^(d<<1) factors as sigmaP (x) sigmaQ (x) condflip(wire5->wire6):
// sigmaP/sigmaQ are folded into the NEXT matmul's matrix (W[a][c]=R[a][F6(c)],
// F6 = prefix-xor = sigma^-1); the cond-flip (conditioned on parity(p&63) in
// the stored pre-sigma frame) is an explicit lane-xor-1 exchange via DPP.
// Matrices are weight-only: computed per call by setup_mats into d_ws in
// exact B-fragment order.
//   MFMA 32x32x16 f16 layouts:
//   A[m][k]: m=lane&31, k=8*(lane>>5)+i ; B[k][n]: n=lane&31, k=8*(lane>>5)+i
//   D[m][n]: n=lane&31, m=(reg&3)+8*(reg>>2)+4*(lane>>5), tiles d[mt][nt].
// R5 lesson: mm_step must accumulate DIRECTLY into d (no nd temp + copy) --
// two live f32x16[2][2] arrays = 128 acc regs -> scratch spill (18 MB writes)
// and occupancy collapse to 2 waves/SIMD.
// ============================================================================

__device__ __forceinline__ u32 pkrtz(float a, float b) {
  auto p = __builtin_amdgcn_cvt_pkrtz(a, b);   // __fp16 ext_vector(2)
  return __builtin_bit_cast(u32, p);
}
__device__ __forceinline__ u32 bperm(int addr, u32 v) {
  return (u32)__builtin_amdgcn_ds_bpermute(addr, (int)v);
}
__device__ __forceinline__ float dppx1(float v) {  // lane xor 1 (quad_perm)
  return __int_as_float(__builtin_amdgcn_mov_dpp(__float_as_int(v), 0xB1, 0xF, 0xF, true));
}
__device__ __forceinline__ float dppx2(float v) {
  return __int_as_float(__builtin_amdgcn_mov_dpp(__float_as_int(v), 0x4E, 0xF, 0xF, true));
}
__device__ __forceinline__ float dppx8(float v) {  // row_ror:8 == xor 8
  return __int_as_float(__builtin_amdgcn_mov_dpp(__float_as_int(v), 0x128, 0xF, 0xF, true));
}
template <int PAT>
__device__ __forceinline__ float swzf(float v) {
  return __int_as_float(__builtin_amdgcn_ds_swizzle(__float_as_int(v), PAT));
}
__device__ __forceinline__ float wave_sum(float v) {
  v += dppx1(v);
  v += dppx2(v);
  v += swzf<0x101F>(v);   // xor 4
  v += dppx8(v);
  v += swzf<0x401F>(v);   // xor 16
  v += __shfl_xor(v, 32, 64);
  return v;
}
__device__ __forceinline__ f16x8 asf(const u32 a[4]) {
  u32x4 v; v.x = a[0]; v.y = a[1]; v.z = a[2]; v.w = a[3];
  return __builtin_bit_cast(f16x8, v);
}
__device__ __forceinline__ f16x8 ldB(const u32* __restrict__ p, int off) {
  u32x4 v = *(const u32x4*)(p + off);
  return __builtin_bit_cast(f16x8, v);
}

// ---------- setup: 12 matrices (fp16, B-fragment order) from weights --------
// 96 blocks: 8 blocks per matrix, 1 entry per thread (keeps this dispatch ~2us)
__global__ void setup_mats(const float* __restrict__ weights, u32* __restrict__ Bbuf) {
  const int mm = blockIdx.x >> 3;   // 0..11 ; layer = mm>>1, side: 0=P,1=Q
  const int l  = mm >> 1;
  const int qs = mm & 1;
  __shared__ float c6[6], s6[6];
  if (threadIdx.x < 6) {
    float h = 0.5f * weights[l * NQ + qs * 6 + threadIdx.x];
    c6[threadIdx.x] = cosf(h);
    s6[threadIdx.x] = sinf(h);
  }
  __syncthreads();
  const int t = (blockIdx.x & 7) * 256 + threadIdx.x;   // 0..2047
  const int lane = (t >> 2) & 63;
  const int fk   = t >> 8;          // nt*4 + kt
  const int kt   = fk & 3;
  const int nt   = fk >> 2;
  const int n     = nt * 32 + (lane & 31);
  const int kbase = kt * 16 + (lane >> 5) * 8 + (t & 3) * 2;
  float v[2];
  #pragma unroll
  for (int u = 0; u < 2; ++u) {
    int k = kbase + u;
    int bb = k;
    if (l >= 1) { bb ^= bb << 1; bb ^= bb << 2; bb ^= bb << 4; bb &= 63; } // F6 = prefix-xor
    float prod = 1.f;
    #pragma unroll
    for (int w = 0; w < 6; ++w) {
      const int aw = (n >> w) & 1, bw = (bb >> w) & 1;
      prod *= (aw == bw) ? c6[w] : (aw ? s6[w] : -s6[w]);  // RY: [[c,-s],[s,c]]
    }
    v[u] = prod;
  }
  Bbuf[mm * 2048 + t] = pkrtz(v[0], v[1]);
}

// ---------- one matmul step: repack prev D -> A frags, 16 MFMA --------------
// d's old value is fully consumed into fr before the first MFMA, so we
// accumulate directly back into d (no temp array).
__device__ __forceinline__ void mm_step(f32x16 (&d)[2][2], const u32* __restrict__ Bl,
                                        bool hi, int axor) {
  u32 fr[2][4][4];
  #pragma unroll
  for (int kt = 0; kt < 4; ++kt) {
    const int s  = kt >> 1;
    const int b0 = 4 * ((2 * kt) & 3);
    const int b1 = 4 * ((2 * kt + 1) & 3);
    #pragma unroll
    for (int mt = 0; mt < 2; ++mt) {
      u32 p0a = pkrtz(d[s][mt][b0 + 0], d[s][mt][b0 + 1]);
      u32 p0b = pkrtz(d[s][mt][b0 + 2], d[s][mt][b0 + 3]);
      u32 p1a = pkrtz(d[s][mt][b1 + 0], d[s][mt][b1 + 1]);
      u32 p1b = pkrtz(d[s][mt][b1 + 2], d[s][mt][b1 + 3]);
      u32 x0a = bperm(axor, p0a), x0b = bperm(axor, p0b);
      u32 x1a = bperm(axor, p1a), x1b = bperm(axor, p1b);
      fr[mt][kt][0] = hi ? x1a : p0a;
      fr[mt][kt][1] = hi ? x1b : p0b;
      fr[mt][kt][2] = hi ? p1a : x0a;
      fr[mt][kt][3] = hi ? p1b : x0b;
    }
  }
  #pragma unroll
  for (int kt = 0; kt < 4; ++kt) {
    f16x8 A0 = asf(fr[0][kt]);
    f16x8 A1 = asf(fr[1][kt]);
    f16x8 B0 = ldB(Bl, (0 * 4 + kt) * 256);
    f16x8 B1 = ldB(Bl, (1 * 4 + kt) * 256);
    if (kt == 0) {
      f32x16 z{};
      d[0][0] = __builtin_amdgcn_mfma_f32_32x32x16_f16(A0, B0, z, 0, 0, 0);
      d[0][1] = __builtin_amdgcn_mfma_f32_32x32x16_f16(A0, B1, z, 0, 0, 0);
      d[1][0] = __builtin_amdgcn_mfma_f32_32x32x16_f16(A1, B0, z, 0, 0, 0);
      d[1][1] = __builtin_amdgcn_mfma_f32_32x32x16_f16(A1, B1, z, 0, 0, 0);
    } else {
      d[0][0] = __builtin_amdgcn_mfma_f32_32x32x16_f16(A0, B0, d[0][0], 0, 0, 0);
      d[0][1] = __builtin_amdgcn_mfma_f32_32x32x16_f16(A0, B1, d[0][1], 0, 0, 0);
      d[1][0] = __builtin_amdgcn_mfma_f32_32x32x16_f16(A1, B0, d[1][0], 0, 0, 0);
      d[1][1] = __builtin_amdgcn_mfma_f32_32x32x16_f16(A1, B1, d[1][1], 0, 0, 0);
    }
  }
}

// ---------- cond-flip: wire5 (P) controls wire6 (Q) lane-xor-1 --------------
__device__ __forceinline__ void flip_step(f32x16 (&d)[2][2], bool hi) {
  #pragma unroll
  for (int mt = 0; mt < 2; ++mt)
    #pragma unroll
    for (int nt = 0; nt < 2; ++nt)
      #pragma unroll
      for (int r = 0; r < 16; ++r) {
        const int par0 = (__builtin_popcount(r & 3) + __builtin_popcount(r >> 2) + mt) & 1;
        float cur = d[mt][nt][r];
        float partner = dppx1(cur);
        const bool cond = par0 ? !hi : hi;
        d[mt][nt][r] = cond ? partner : cur;
      }
}

__global__ void __launch_bounds__(256) __attribute__((amdgpu_waves_per_eu(3, 4)))
dqc_main(const float* __restrict__ x,
         const float* __restrict__ pre_w,
         const float* __restrict__ pre_b,
         const float* __restrict__ post_w,
         const float* __restrict__ post_b,
         const u32* __restrict__ Bbuf,
         float* __restrict__ out)
{
  const int lane = threadIdx.x & 63;
  const bool hi  = lane >= 32;
  const int b    = blockIdx.x * 4 + (threadIdx.x >> 6);
  const int axor = (lane ^ 32) << 2;

  // ---- pre-GEMM: pre[w] = x[b,:] . pre_w[w,:]
  float acc[NQ];
  const float* xr = x + (size_t)b * DIN + lane * 8;
  const float4 xa = *(const float4*)(xr);
  const float4 xb = *(const float4*)(xr + 4);
  #pragma unroll
  for (int w = 0; w < NQ; ++w) {
    const float* wr = pre_w + w * DIN + lane * 8;
    const float4 wa = *(const float4*)(wr);
    const float4 wb = *(const float4*)(wr + 4);
    acc[w] = xa.x * wa.x + xa.y * wa.y + xa.z * wa.z + xa.w * wa.w
           + xb.x * wb.x + xb.y * wb.y + xb.z * wb.z + xb.w * wb.w;
  }
  #pragma unroll
  for (int w = 0; w < NQ; ++w) acc[w] = wave_sum(acc[w]);

  const float PI_4 = 0.78539816339744830962f;
  const float INV_SQRT2 = 0.70710678118654752440f;
  float v0[NQ], v1[NQ];
  #pragma unroll
  for (int w = 0; w < NQ; ++w) {
    float h = (acc[w] + pre_b[w]) * PI_4;
    float s, c;
    sincosf(h, &s, &c);
    v0[w] = (c - s) * INV_SQRT2;
    v1[w] = (c + s) * INV_SQRT2;
  }

  // ---- initial product state, built directly as MM0 A-frags:
  // A[m=q][k=p], q = 32*mt + (lane&31), p = 16*kt + 8*hi + j
  float base8[8];
  #pragma unroll
  for (int j = 0; j < 8; ++j)
    base8[j] = ((j & 1) ? v1[0] : v0[0]) * ((j & 2) ? v1[1] : v0[1]) * ((j & 4) ? v1[2] : v0[2]);
  float hiP[4];
  #pragma unroll
  for (int kt = 0; kt < 4; ++kt)
    hiP[kt] = (hi ? v1[3] : v0[3]) * ((kt & 1) ? v1[4] : v0[4]) * ((kt & 2) ? v1[5] : v0[5]);
  const float qb = ((lane & 1) ? v1[6] : v0[6]) * ((lane & 2) ? v1[7] : v0[7])
                 * ((lane & 4) ? v1[8] : v0[8]) * ((lane & 8) ? v1[9] : v0[9])
                 * ((lane & 16) ? v1[10] : v0[10]);
  const float qm0 = qb * v0[11], qm1 = qb * v1[11];

  f32x16 d[2][2];
  {
    const u32* Bl = Bbuf + lane * 4;   // mm = 0
    #pragma unroll
    for (int kt = 0; kt < 4; ++kt) {
      u32 a0[4], a1[4];
      #pragma unroll
      for (int dw = 0; dw < 4; ++dw) {
        const float e0 = base8[2 * dw] * hiP[kt];
        const float e1 = base8[2 * dw + 1] * hiP[kt];
        a0[dw] = pkrtz(qm0 * e0, qm0 * e1);
        a1[dw] = pkrtz(qm1 * e0, qm1 * e1);
      }
      f16x8 A0 = asf(a0), A1 = asf(a1);
      f16x8 B0 = ldB(Bl, (0 * 4 + kt) * 256);
      f16x8 B1 = ldB(Bl, (1 * 4 + kt) * 256);
      if (kt == 0) {
        f32x16 z{};
        d[0][0] = __builtin_amdgcn_mfma_f32_32x32x16_f16(A0, B0, z, 0, 0, 0);
        d[0][1] = __builtin_amdgcn_mfma_f32_32x32x16_f16(A0, B1, z, 0, 0, 0);
        d[1][0] = __builtin_amdgcn_mfma_f32_32x32x16_f16(A1, B0, z, 0, 0, 0);
        d[1][1] = __builtin_amdgcn_mfma_f32_32x32x16_f16(A1, B1, z, 0, 0, 0);
      } else {
        d[0][0] = __builtin_amdgcn_mfma_f32_32x32x16_f16(A0, B0, d[0][0], 0, 0, 0);
        d[0][1] = __builtin_amdgcn_mfma_f32_32x32x16_f16(A0, B1, d[0][1], 0, 0, 0);
        d[1][0] = __builtin_amdgcn_mfma_f32_32x32x16_f16(A1, B0, d[1][0], 0, 0, 0);
        d[1][1] = __builtin_amdgcn_mfma_f32_32x32x16_f16(A1, B1, d[1][1], 0, 0, 0);
      }
    }
  }

  // ---- MM 1..11, cond-flip after each odd (Q-side) matmul
  #pragma clang loop unroll(disable)
  for (int t = 1; t < 12; ++t) {
    mm_step(d, Bbuf + t * 2048 + lane * 4, hi, axor);
    if (t & 1) flip_step(d, hi);
  }

  // ---- measurement (state: m=p, n=q', both in pre-sigma frames ->
  //      true bit w = prefix-parity of stored bits 0..w)
  float tot = 0.f, s0 = 0.f;
  float zp0 = 0.f, zp1 = 0.f, zp3 = 0.f, zp4 = 0.f, zp5 = 0.f;
  #pragma unroll
  for (int mt = 0; mt < 2; ++mt)
    #pragma unroll
    for (int nt = 0; nt < 2; ++nt)
      #pragma unroll
      for (int r = 0; r < 16; ++r) {
        float v = d[mt][nt][r];
        float sq = v * v;
        tot += sq;
        if (nt == 0) s0 += sq;
        const int c0 = r & 1;
        const int c1 = (r ^ (r >> 1)) & 1;
        const int c3 = c1 ^ ((r >> 2) & 1);
        const int c4 = c3 ^ ((r >> 3) & 1);
        const int c5 = c4 ^ mt;
        zp0 += c0 ? -sq : sq;
        zp1 += c1 ? -sq : sq;
        zp3 += c3 ? -sq : sq;
        zp4 += c4 ? -sq : sq;
        zp5 += c5 ? -sq : sq;
      }
  const float sgnhi = hi ? -1.f : 1.f;   // p2 = l5 enters wires >= 2
  float z[12];
  z[0] = zp0;
  z[1] = zp1;
  z[2] = sgnhi * zp1;   // reg-part of wire2 mask == wire1 mask
  z[3] = sgnhi * zp3;
  z[4] = sgnhi * zp4;
  z[5] = sgnhi * zp5;
  #pragma unroll
  for (int j = 0; j < 5; ++j) {
    const int par = __builtin_popcount(lane & ((2 << j) - 1)) & 1;
    z[6 + j] = par ? -tot : tot;
  }
  {
    const int par = __builtin_popcount(lane & 31) & 1;  // q'5 = nt handled via s0
    z[11] = (par ? -1.f : 1.f) * (2.f * s0 - tot);
  }
  const float tots = wave_sum(tot);
  #pragma unroll
  for (int w = 0; w < 12; ++w) z[w] = wave_sum(z[w]);

  if (lane == 0) {
    const float inv = 1.0f / tots;
    float o = post_b[0];
    #pragma unroll
    for (int w = 0; w < 12; ++w) o = fmaf(z[w] * inv, post_w[w], o);
    out[b] = o;
  }
}

extern "C" void kernel_launch(void* const* d_in, const int* in_sizes, int n_in,
                              void* d_out, int out_size, void* d_ws, size_t ws_size,
                              hipStream_t stream) {
  (void)in_sizes; (void)n_in; (void)out_size; (void)ws_size;
  const float* x       = (const float*)d_in[0];
  const float* pre_w   = (const float*)d_in[1];
  const float* pre_b   = (const float*)d_in[2];
  const float* weights = (const float*)d_in[3];
  const float* post_w  = (const float*)d_in[4];
  const float* post_b  = (const float*)d_in[5];
  float* out = (float*)d_out;
  u32* Bbuf = (u32*)d_ws;   // 12 * 2048 dwords = 96 KiB

  setup_mats<<<96, 256, 0, stream>>>(weights, Bbuf);
  dqc_main<<<BATCHN / 4, 256, 0, stream>>>(x, pre_w, pre_b, post_w, post_b, Bbuf, out);
}

// Round 8
// 137.788 us; speedup vs baseline: 1.9591x; 1.0036x over previous
//
#include <hip/hip_runtime.h>
#include <math.h>

#define NQ 12
#define NL 6
#define BATCHN 8192
#define DIN 512

typedef _Float16 f16;
typedef __attribute__((ext_vector_type(8)))  _Float16 f16x8;
typedef __attribute__((ext_vector_type(16))) float    f32x16;
typedef unsigned int u32;
typedef __attribute__((ext_vector_type(4))) u32 u32x4;

// ============================================================================
// 12-matmul formulation. State = 64x64 (P-factor: wires 0-5, Q-factor: wires
// 6-11). MFMA contracts the reg-resident factor and swaps residency, so
// alternating matmuls apply Kron(6 RYs) to each factor. CNOT chain
// sigma(d)=d^(d<<1) factors as sigmaP (x) sigmaQ (x) condflip(wire5->wire6):
// sigmaP/sigmaQ are folded into the NEXT matmul's matrix (W[a][c]=R[a][F6(c)],
// F6 = prefix-xor = sigma^-1); the cond-flip (conditioned on parity(p&63) in
// the stored pre-sigma frame) is a row-masked DPP lane-xor-1.
// Matrices are weight-only: computed per call by setup_mats into d_ws in
// exact B-fragment order.
//   MFMA 32x32x16 f16 layouts:
//   A[m][k]: m=lane&31, k=8*(lane>>5)+i ; B[k][n]: n=lane&31, k=8*(lane>>5)+i
//   D[m][n]: n=lane&31, m=(reg&3)+8*(reg>>2)+4*(lane>>5), tiles d[mt][nt].
// R5 lesson: mm_step must accumulate DIRECTLY into d (no nd temp + copy).
// R6 lesson: waves_per_eu(3,4) pinned ~2.75 waves/SIMD -> latency-bound;
//   flip cond (par0 ^ hi) is DPP-row-aligned -> use update_dpp row_mask
//   (1 inst/element instead of dpp+cndmask).
// ============================================================================

__device__ __forceinline__ u32 pkrtz(float a, float b) {
  auto p = __builtin_amdgcn_cvt_pkrtz(a, b);   // __fp16 ext_vector(2)
  return __builtin_bit_cast(u32, p);
}
__device__ __forceinline__ u32 bperm(int addr, u32 v) {
  return (u32)__builtin_amdgcn_ds_bpermute(addr, (int)v);
}
__device__ __forceinline__ float dppx1(float v) {  // lane xor 1 (quad_perm)
  return __int_as_float(__builtin_amdgcn_mov_dpp(__float_as_int(v), 0xB1, 0xF, 0xF, true));
}
__device__ __forceinline__ float dppx2(float v) {
  return __int_as_float(__builtin_amdgcn_mov_dpp(__float_as_int(v), 0x4E, 0xF, 0xF, true));
}
__device__ __forceinline__ float dppx8(float v) {  // row_ror:8 == xor 8
  return __int_as_float(__builtin_amdgcn_mov_dpp(__float_as_int(v), 0x128, 0xF, 0xF, true));
}
// conditional lane-xor-1 exchange, applied ONLY in DPP rows selected by RMASK
// (row = 16 lanes; rows 2,3 = lanes 32-63). Non-selected rows keep old value.
template <int RMASK>
__device__ __forceinline__ float flipsel(float v) {
  return __int_as_float(__builtin_amdgcn_update_dpp(
      __float_as_int(v), __float_as_int(v), 0xB1, RMASK, 0xF, false));
}
template <int PAT>
__device__ __forceinline__ float swzf(float v) {
  return __int_as_float(__builtin_amdgcn_ds_swizzle(__float_as_int(v), PAT));
}
__device__ __forceinline__ float wave_sum(float v) {
  v += dppx1(v);
  v += dppx2(v);
  v += swzf<0x101F>(v);   // xor 4
  v += dppx8(v);
  v += swzf<0x401F>(v);   // xor 16
  v += __shfl_xor(v, 32, 64);
  return v;
}
__device__ __forceinline__ f16x8 asf(const u32 a[4]) {
  u32x4 v; v.x = a[0]; v.y = a[1]; v.z = a[2]; v.w = a[3];
  return __builtin_bit_cast(f16x8, v);
}
__device__ __forceinline__ f16x8 ldB(const u32* __restrict__ p, int off) {
  u32x4 v = *(const u32x4*)(p + off);
  return __builtin_bit_cast(f16x8, v);
}

// ---------- setup: 12 matrices (fp16, B-fragment order) from weights --------
// 96 blocks: 8 blocks per matrix, 1 entry per thread (keeps this dispatch ~2us)
__global__ void setup_mats(const float* __restrict__ weights, u32* __restrict__ Bbuf) {
  const int mm = blockIdx.x >> 3;   // 0..11 ; layer = mm>>1, side: 0=P,1=Q
  const int l  = mm >> 1;
  const int qs = mm & 1;
  __shared__ float c6[6], s6[6];
  if (threadIdx.x < 6) {
    float h = 0.5f * weights[l * NQ + qs * 6 + threadIdx.x];
    c6[threadIdx.x] = cosf(h);
    s6[threadIdx.x] = sinf(h);
  }
  __syncthreads();
  const int t = (blockIdx.x & 7) * 256 + threadIdx.x;   // 0..2047
  const int lane = (t >> 2) & 63;
  const int fk   = t >> 8;          // nt*4 + kt
  const int kt   = fk & 3;
  const int nt   = fk >> 2;
  const int n     = nt * 32 + (lane & 31);
  const int kbase = kt * 16 + (lane >> 5) * 8 + (t & 3) * 2;
  float v[2];
  #pragma unroll
  for (int u = 0; u < 2; ++u) {
    int k = kbase + u;
    int bb = k;
    if (l >= 1) { bb ^= bb << 1; bb ^= bb << 2; bb ^= bb << 4; bb &= 63; } // F6 = prefix-xor
    float prod = 1.f;
    #pragma unroll
    for (int w = 0; w < 6; ++w) {
      const int aw = (n >> w) & 1, bw = (bb >> w) & 1;
      prod *= (aw == bw) ? c6[w] : (aw ? s6[w] : -s6[w]);  // RY: [[c,-s],[s,c]]
    }
    v[u] = prod;
  }
  Bbuf[mm * 2048 + t] = pkrtz(v[0], v[1]);
}

// ---------- one matmul step: repack prev D -> A frags, 16 MFMA --------------
// d's old value is fully consumed into fr before the first MFMA, so we
// accumulate directly back into d (no temp array).
__device__ __forceinline__ void mm_step(f32x16 (&d)[2][2], const u32* __restrict__ Bl,
                                        bool hi, int axor) {
  u32 fr[2][4][4];
  #pragma unroll
  for (int kt = 0; kt < 4; ++kt) {
    const int s  = kt >> 1;
    const int b0 = 4 * ((2 * kt) & 3);
    const int b1 = 4 * ((2 * kt + 1) & 3);
    #pragma unroll
    for (int mt = 0; mt < 2; ++mt) {
      u32 p0a = pkrtz(d[s][mt][b0 + 0], d[s][mt][b0 + 1]);
      u32 p0b = pkrtz(d[s][mt][b0 + 2], d[s][mt][b0 + 3]);
      u32 p1a = pkrtz(d[s][mt][b1 + 0], d[s][mt][b1 + 1]);
      u32 p1b = pkrtz(d[s][mt][b1 + 2], d[s][mt][b1 + 3]);
      u32 x0a = bperm(axor, p0a), x0b = bperm(axor, p0b);
      u32 x1a = bperm(axor, p1a), x1b = bperm(axor, p1b);
      fr[mt][kt][0] = hi ? x1a : p0a;
      fr[mt][kt][1] = hi ? x1b : p0b;
      fr[mt][kt][2] = hi ? p1a : x0a;
      fr[mt][kt][3] = hi ? p1b : x0b;
    }
  }
  #pragma unroll
  for (int kt = 0; kt < 4; ++kt) {
    f16x8 A0 = asf(fr[0][kt]);
    f16x8 A1 = asf(fr[1][kt]);
    f16x8 B0 = ldB(Bl, (0 * 4 + kt) * 256);
    f16x8 B1 = ldB(Bl, (1 * 4 + kt) * 256);
    if (kt == 0) {
      f32x16 z{};
      d[0][0] = __builtin_amdgcn_mfma_f32_32x32x16_f16(A0, B0, z, 0, 0, 0);
      d[0][1] = __builtin_amdgcn_mfma_f32_32x32x16_f16(A0, B1, z, 0, 0, 0);
      d[1][0] = __builtin_amdgcn_mfma_f32_32x32x16_f16(A1, B0, z, 0, 0, 0);
      d[1][1] = __builtin_amdgcn_mfma_f32_32x32x16_f16(A1, B1, z, 0, 0, 0);
    } else {
      d[0][0] = __builtin_amdgcn_mfma_f32_32x32x16_f16(A0, B0, d[0][0], 0, 0, 0);
      d[0][1] = __builtin_amdgcn_mfma_f32_32x32x16_f16(A0, B1, d[0][1], 0, 0, 0);
      d[1][0] = __builtin_amdgcn_mfma_f32_32x32x16_f16(A1, B0, d[1][0], 0, 0, 0);
      d[1][1] = __builtin_amdgcn_mfma_f32_32x32x16_f16(A1, B1, d[1][1], 0, 0, 0);
    }
  }
}

// ---------- cond-flip: wire5 (P) controls wire6 (Q) lane-xor-1 --------------
// cond = par0(r,mt) XOR hi; hi == DPP rows 2,3 -> row-masked update_dpp,
// 1 instruction per element (masked-off rows keep old value).
__device__ __forceinline__ void flip_step(f32x16 (&d)[2][2]) {
  #pragma unroll
  for (int mt = 0; mt < 2; ++mt)
    #pragma unroll
    for (int nt = 0; nt < 2; ++nt)
      #pragma unroll
      for (int r = 0; r < 16; ++r) {
        const int par0 = (__builtin_popcount(r & 3) + __builtin_popcount(r >> 2) + mt) & 1;
        if (par0)
          d[mt][nt][r] = flipsel<0x3>(d[mt][nt][r]);   // flip lanes 0-31
        else
          d[mt][nt][r] = flipsel<0xC>(d[mt][nt][r]);   // flip lanes 32-63
      }
}

__global__ void __launch_bounds__(256) __attribute__((amdgpu_waves_per_eu(4)))
dqc_main(const float* __restrict__ x,
         const float* __restrict__ pre_w,
         const float* __restrict__ pre_b,
         const float* __restrict__ post_w,
         const float* __restrict__ post_b,
         const u32* __restrict__ Bbuf,
         float* __restrict__ out)
{
  const int lane = threadIdx.x & 63;
  const bool hi  = lane >= 32;
  const int b    = blockIdx.x * 4 + (threadIdx.x >> 6);
  const int axor = (lane ^ 32) << 2;

  // ---- pre-GEMM: pre[w] = x[b,:] . pre_w[w,:]
  float acc[NQ];
  const float* xr = x + (size_t)b * DIN + lane * 8;
  const float4 xa = *(const float4*)(xr);
  const float4 xb = *(const float4*)(xr + 4);
  #pragma unroll
  for (int w = 0; w < NQ; ++w) {
    const float* wr = pre_w + w * DIN + lane * 8;
    const float4 wa = *(const float4*)(wr);
    const float4 wb = *(const float4*)(wr + 4);
    acc[w] = xa.x * wa.x + xa.y * wa.y + xa.z * wa.z + xa.w * wa.w
           + xb.x * wb.x + xb.y * wb.y + xb.z * wb.z + xb.w * wb.w;
  }
  #pragma unroll
  for (int w = 0; w < NQ; ++w) acc[w] = wave_sum(acc[w]);

  const float PI_4 = 0.78539816339744830962f;
  const float INV_SQRT2 = 0.70710678118654752440f;
  float v0[NQ], v1[NQ];
  #pragma unroll
  for (int w = 0; w < NQ; ++w) {
    float h = (acc[w] + pre_b[w]) * PI_4;
    float s, c;
    sincosf(h, &s, &c);
    v0[w] = (c - s) * INV_SQRT2;
    v1[w] = (c + s) * INV_SQRT2;
  }

  // ---- initial product state, built directly as MM0 A-frags:
  // A[m=q][k=p], q = 32*mt + (lane&31), p = 16*kt + 8*hi + j
  float base8[8];
  #pragma unroll
  for (int j = 0; j < 8; ++j)
    base8[j] = ((j & 1) ? v1[0] : v0[0]) * ((j & 2) ? v1[1] : v0[1]) * ((j & 4) ? v1[2] : v0[2]);
  float hiP[4];
  #pragma unroll
  for (int kt = 0; kt < 4; ++kt)
    hiP[kt] = (hi ? v1[3] : v0[3]) * ((kt & 1) ? v1[4] : v0[4]) * ((kt & 2) ? v1[5] : v0[5]);
  const float qb = ((lane & 1) ? v1[6] : v0[6]) * ((lane & 2) ? v1[7] : v0[7])
                 * ((lane & 4) ? v1[8] : v0[8]) * ((lane & 8) ? v1[9] : v0[9])
                 * ((lane & 16) ? v1[10] : v0[10]);
  const float qm0 = qb * v0[11], qm1 = qb * v1[11];

  f32x16 d[2][2];
  {
    const u32* Bl = Bbuf + lane * 4;   // mm = 0
    #pragma unroll
    for (int kt = 0; kt < 4; ++kt) {
      u32 a0[4], a1[4];
      #pragma unroll
      for (int dw = 0; dw < 4; ++dw) {
        const float e0 = base8[2 * dw] * hiP[kt];
        const float e1 = base8[2 * dw + 1] * hiP[kt];
        a0[dw] = pkrtz(qm0 * e0, qm0 * e1);
        a1[dw] = pkrtz(qm1 * e0, qm1 * e1);
      }
      f16x8 A0 = asf(a0), A1 = asf(a1);
      f16x8 B0 = ldB(Bl, (0 * 4 + kt) * 256);
      f16x8 B1 = ldB(Bl, (1 * 4 + kt) * 256);
      if (kt == 0) {
        f32x16 z{};
        d[0][0] = __builtin_amdgcn_mfma_f32_32x32x16_f16(A0, B0, z, 0, 0, 0);
        d[0][1] = __builtin_amdgcn_mfma_f32_32x32x16_f16(A0, B1, z, 0, 0, 0);
        d[1][0] = __builtin_amdgcn_mfma_f32_32x32x16_f16(A1, B0, z, 0, 0, 0);
        d[1][1] = __builtin_amdgcn_mfma_f32_32x32x16_f16(A1, B1, z, 0, 0, 0);
      } else {
        d[0][0] = __builtin_amdgcn_mfma_f32_32x32x16_f16(A0, B0, d[0][0], 0, 0, 0);
        d[0][1] = __builtin_amdgcn_mfma_f32_32x32x16_f16(A0, B1, d[0][1], 0, 0, 0);
        d[1][0] = __builtin_amdgcn_mfma_f32_32x32x16_f16(A1, B0, d[1][0], 0, 0, 0);
        d[1][1] = __builtin_amdgcn_mfma_f32_32x32x16_f16(A1, B1, d[1][1], 0, 0, 0);
      }
    }
  }

  // ---- MM 1..11, cond-flip after each odd (Q-side) matmul
  #pragma clang loop unroll(disable)
  for (int t = 1; t < 12; ++t) {
    mm_step(d, Bbuf + t * 2048 + lane * 4, hi, axor);
    if (t & 1) flip_step(d);
  }

  // ---- measurement (state: m=p, n=q', both in pre-sigma frames ->
  //      true bit w = prefix-parity of stored bits 0..w)
  float tot = 0.f, s0 = 0.f;
  float zp0 = 0.f, zp1 = 0.f, zp3 = 0.f, zp4 = 0.f, zp5 = 0.f;
  #pragma unroll
  for (int mt = 0; mt < 2; ++mt)
    #pragma unroll
    for (int nt = 0; nt < 2; ++nt)
      #pragma unroll
      for (int r = 0; r < 16; ++r) {
        float v = d[mt][nt][r];
        float sq = v * v;
        tot += sq;
        if (nt == 0) s0 += sq;
        const int c0 = r & 1;
        const int c1 = (r ^ (r >> 1)) & 1;
        const int c3 = c1 ^ ((r >> 2) & 1);
        const int c4 = c3 ^ ((r >> 3) & 1);
        const int c5 = c4 ^ mt;
        zp0 += c0 ? -sq : sq;
        zp1 += c1 ? -sq : sq;
        zp3 += c3 ? -sq : sq;
        zp4 += c4 ? -sq : sq;
        zp5 += c5 ? -sq : sq;
      }
  const float sgnhi = hi ? -1.f : 1.f;   // p2 = l5 enters wires >= 2
  float z[12];
  z[0] = zp0;
  z[1] = zp1;
  z[2] = sgnhi * zp1;   // reg-part of wire2 mask == wire1 mask
  z[3] = sgnhi * zp3;
  z[4] = sgnhi * zp4;
  z[5] = sgnhi * zp5;
  #pragma unroll
  for (int j = 0; j < 5; ++j) {
    const int par = __builtin_popcount(lane & ((2 << j) - 1)) & 1;
    z[6 + j] = par ? -tot : tot;
  }
  {
    const int par = __builtin_popcount(lane & 31) & 1;  // q'5 = nt handled via s0
    z[11] = (par ? -1.f : 1.f) * (2.f * s0 - tot);
  }
  const float tots = wave_sum(tot);
  #pragma unroll
  for (int w = 0; w < 12; ++w) z[w] = wave_sum(z[w]);

  if (lane == 0) {
    const float inv = 1.0f / tots;
    float o = post_b[0];
    #pragma unroll
    for (int w = 0; w < 12; ++w) o = fmaf(z[w] * inv, post_w[w], o);
    out[b] = o;
  }
}

extern "C" void kernel_launch(void* const* d_in, const int* in_sizes, int n_in,
                              void* d_out, int out_size, void* d_ws, size_t ws_size,
                              hipStream_t stream) {
  (void)in_sizes; (void)n_in; (void)out_size; (void)ws_size;
  const float* x       = (const float*)d_in[0];
  const float* pre_w   = (const float*)d_in[1];
  const float* pre_b   = (const float*)d_in[2];
  const float* weights = (const float*)d_in[3];
  const float* post_w  = (const float*)d_in[4];
  const float* post_b  = (const float*)d_in[5];
  float* out = (float*)d_out;
  u32* Bbuf = (u32*)d_ws;   // 12 * 2048 dwords = 96 KiB

  setup_mats<<<96, 256, 0, stream>>>(weights, Bbuf);
  dqc_main<<<BATCHN / 4, 256, 0, stream>>>(x, pre_w, pre_b, post_w, post_b, Bbuf, out);
}

// Round 10
// 129.420 us; speedup vs baseline: 2.0858x; 1.0647x over previous
//
#include <hip/hip_runtime.h>
#include <math.h>

#define NQ 12
#define NL 6
#define BATCHN 8192
#define DIN 512

typedef _Float16 f16;
typedef __attribute__((ext_vector_type(8)))  _Float16 f16x8;
typedef __attribute__((ext_vector_type(16))) float    f32x16;
typedef unsigned int u32;
typedef __attribute__((ext_vector_type(4))) u32 u32x4;
typedef __attribute__((ext_vector_type(2))) int i32x2;

// ============================================================================
// 12-matmul formulation. State = 64x64 (P-factor: wires 0-5, Q-factor: wires
// 6-11). MFMA contracts the reg-resident factor and swaps residency, so
// alternating matmuls apply Kron(6 RYs) to each factor. CNOT chain
// sigma(d)=d^(d<<1) factors as sigmaP (x) sigmaQ (x) condflip(wire5->wire6):
// sigmaP/sigmaQ are folded into the NEXT matmul's matrix; the cond-flip
// (lane-xor-1 conditioned on parity(p)) is folded into (a) the next step's
// repack at the packed-word level (1 dpp + 1 bfi per word), and (b) for the
// final layer, into the measurement sign algebra (parity-split accumulators).
//   MFMA 32x32x16 f16 layouts:
//   A[m][k]: m=lane&31, k=8*(lane>>5)+i ; B[k][n]: n=lane&31, k=8*(lane>>5)+i
//   D[m][n]: n=lane&31, m=(reg&3)+8*(reg>>2)+4*(lane>>5), tiles d[mt][nt].
// R5: accumulate directly into d (no temp) or scratch-spill.
// R7: repack was 32 bperm(DS) + 32 cndmask per step -> dominated VALU/DS.
// R8: v_permlane32_swap_b32 produces BOTH fr words in 1 VALU inst. FAILED:
//   fold parity class used the old n-tile index (mt) instead of the old
//   m-tile index (s = kt>>1) -- the flip condition lives on the m (=p)
//   dimension, d[s][mt] has first index = m-tile. R9 fixes ka/kc to use s.
// ============================================================================

__device__ __forceinline__ u32 pkrtz(float a, float b) {
  auto p = __builtin_amdgcn_cvt_pkrtz(a, b);   // __fp16 ext_vector(2)
  return __builtin_bit_cast(u32, p);
}
__device__ __forceinline__ u32 bperm(int addr, u32 v) {
  return (u32)__builtin_amdgcn_ds_bpermute(addr, (int)v);
}
__device__ __forceinline__ float dppx1(float v) {  // lane xor 1 (quad_perm)
  return __int_as_float(__builtin_amdgcn_mov_dpp(__float_as_int(v), 0xB1, 0xF, 0xF, true));
}
__device__ __forceinline__ u32 dppx1u(u32 v) {
  return (u32)__builtin_amdgcn_mov_dpp((int)v, 0xB1, 0xF, 0xF, true);
}
__device__ __forceinline__ float dppx2(float v) {
  return __int_as_float(__builtin_amdgcn_mov_dpp(__float_as_int(v), 0x4E, 0xF, 0xF, true));
}
__device__ __forceinline__ float dppx8(float v) {  // row_ror:8 == xor 8
  return __int_as_float(__builtin_amdgcn_mov_dpp(__float_as_int(v), 0x128, 0xF, 0xF, true));
}
template <int PAT>
__device__ __forceinline__ float swzf(float v) {
  return __int_as_float(__builtin_amdgcn_ds_swizzle(__float_as_int(v), PAT));
}
__device__ __forceinline__ float wave_sum(float v) {
  v += dppx1(v);
  v += dppx2(v);
  v += swzf<0x101F>(v);   // xor 4
  v += dppx8(v);
  v += swzf<0x401F>(v);   // xor 16
  v += __shfl_xor(v, 32, 64);
  return v;
}
__device__ __forceinline__ f16x8 asf(const u32 a[4]) {
  u32x4 v; v.x = a[0]; v.y = a[1]; v.z = a[2]; v.w = a[3];
  return __builtin_bit_cast(f16x8, v);
}
__device__ __forceinline__ f16x8 ldB(const u32* __restrict__ p, int off) {
  u32x4 v = *(const u32x4*)(p + off);
  return __builtin_bit_cast(f16x8, v);
}

// half-swap across the lane-32 boundary: returns the two A-frag words.
// vdst_new = {lo: a, hi: b[lane-32]}, vsrc_new = {lo: a[lane+32], hi: b}
#if __has_builtin(__builtin_amdgcn_permlane32_swap)
__device__ __forceinline__ void pswap(u32& a, u32& b) {
  i32x2 r = __builtin_amdgcn_permlane32_swap((int)a, (int)b, false, false);
  a = (u32)r.x; b = (u32)r.y;
}
#else
#define PSWAP_FALLBACK 1
__device__ __forceinline__ void pswap_fb(u32& a, u32& b, bool hi, int axor) {
  u32 xa = bperm(axor, a), xb = bperm(axor, b);
  u32 na = hi ? xb : a;
  u32 nb = hi ? b : xa;
  a = na; b = nb;
}
#endif

// conditional lane-xor-1 on a packed word: the two f16 halves have opposite
// flip conditions (consecutive m parity); mask selects which half takes the
// DPP partner (bfi idiom).
__device__ __forceinline__ u32 foldw(u32 w, u32 m) {
  u32 partner = dppx1u(w);
  return (m & partner) | (~m & w);
}

// ---------- setup: 12 matrices (fp16, B-fragment order) from weights --------
__global__ void setup_mats(const float* __restrict__ weights, u32* __restrict__ Bbuf) {
  const int mm = blockIdx.x >> 3;   // 0..11 ; layer = mm>>1, side: 0=P,1=Q
  const int l  = mm >> 1;
  const int qs = mm & 1;
  __shared__ float c6[6], s6[6];
  if (threadIdx.x < 6) {
    float h = 0.5f * weights[l * NQ + qs * 6 + threadIdx.x];
    c6[threadIdx.x] = cosf(h);
    s6[threadIdx.x] = sinf(h);
  }
  __syncthreads();
  const int t = (blockIdx.x & 7) * 256 + threadIdx.x;   // 0..2047
  const int lane = (t >> 2) & 63;
  const int fk   = t >> 8;          // nt*4 + kt
  const int kt   = fk & 3;
  const int nt   = fk >> 2;
  const int n     = nt * 32 + (lane & 31);
  const int kbase = kt * 16 + (lane >> 5) * 8 + (t & 3) * 2;
  float v[2];
  #pragma unroll
  for (int u = 0; u < 2; ++u) {
    int k = kbase + u;
    int bb = k;
    if (l >= 1) { bb ^= bb << 1; bb ^= bb << 2; bb ^= bb << 4; bb &= 63; } // F6 = prefix-xor
    float prod = 1.f;
    #pragma unroll
    for (int w = 0; w < 6; ++w) {
      const int aw = (n >> w) & 1, bw = (bb >> w) & 1;
      prod *= (aw == bw) ? c6[w] : (aw ? s6[w] : -s6[w]);  // RY: [[c,-s],[s,c]]
    }
    v[u] = prod;
  }
  Bbuf[mm * 2048 + t] = pkrtz(v[0], v[1]);
}

// ---------- one matmul step: repack prev D -> A frags, 16 MFMA --------------
// FOLD: apply the previous (Q-side) step's cond-flip at the word level before
// the half-swap. Flip condition for old element (r, m-tile s, lane-bit5 hi):
//   parity = pc(r&3)+pc(r>>2)+s+hi. Word (b+0,b+1): low-half class
//   ka = PAR4[b>>2]+s (high half is ka^1). maskA = class-0 mask, maskB = ~.
template <bool FOLD>
__device__ __forceinline__ void mm_step(f32x16 (&d)[2][2], const u32* __restrict__ Bl,
                                        bool hi, int axor, u32 maskA, u32 maskB) {
  u32 fr[2][4][4];
  #pragma unroll
  for (int kt = 0; kt < 4; ++kt) {
    const int s  = kt >> 1;
    const int b0 = 4 * ((2 * kt) & 3);
    const int b1 = 4 * ((2 * kt + 1) & 3);
    #pragma unroll
    for (int mt = 0; mt < 2; ++mt) {
      u32 p0a = pkrtz(d[s][mt][b0 + 0], d[s][mt][b0 + 1]);
      u32 p0b = pkrtz(d[s][mt][b0 + 2], d[s][mt][b0 + 3]);
      u32 p1a = pkrtz(d[s][mt][b1 + 0], d[s][mt][b1 + 1]);
      u32 p1b = pkrtz(d[s][mt][b1 + 2], d[s][mt][b1 + 3]);
      if (FOLD) {
        const int PAR4[4] = {0, 1, 1, 0};
        const int ka = (PAR4[b0 >> 2] + s) & 1;   // low-half class of p0a (R8 bug: used mt)
        const int kc = (PAR4[b1 >> 2] + s) & 1;   // low-half class of p1a
        p0a = foldw(p0a, ka ? maskB : maskA);
        p0b = foldw(p0b, ka ? maskA : maskB);
        p1a = foldw(p1a, kc ? maskB : maskA);
        p1b = foldw(p1b, kc ? maskA : maskB);
      }
#ifdef PSWAP_FALLBACK
      pswap_fb(p0a, p1a, hi, axor);
      pswap_fb(p0b, p1b, hi, axor);
#else
      pswap(p0a, p1a);
      pswap(p0b, p1b);
#endif
      fr[mt][kt][0] = p0a;
      fr[mt][kt][1] = p0b;
      fr[mt][kt][2] = p1a;
      fr[mt][kt][3] = p1b;
    }
  }
  #pragma unroll
  for (int kt = 0; kt < 4; ++kt) {
    f16x8 A0 = asf(fr[0][kt]);
    f16x8 A1 = asf(fr[1][kt]);
    f16x8 B0 = ldB(Bl, (0 * 4 + kt) * 256);
    f16x8 B1 = ldB(Bl, (1 * 4 + kt) * 256);
    if (kt == 0) {
      f32x16 z{};
      d[0][0] = __builtin_amdgcn_mfma_f32_32x32x16_f16(A0, B0, z, 0, 0, 0);
      d[0][1] = __builtin_amdgcn_mfma_f32_32x32x16_f16(A0, B1, z, 0, 0, 0);
      d[1][0] = __builtin_amdgcn_mfma_f32_32x32x16_f16(A1, B0, z, 0, 0, 0);
      d[1][1] = __builtin_amdgcn_mfma_f32_32x32x16_f16(A1, B1, z, 0, 0, 0);
    } else {
      d[0][0] = __builtin_amdgcn_mfma_f32_32x32x16_f16(A0, B0, d[0][0], 0, 0, 0);
      d[0][1] = __builtin_amdgcn_mfma_f32_32x32x16_f16(A0, B1, d[0][1], 0, 0, 0);
      d[1][0] = __builtin_amdgcn_mfma_f32_32x32x16_f16(A1, B0, d[1][0], 0, 0, 0);
      d[1][1] = __builtin_amdgcn_mfma_f32_32x32x16_f16(A1, B1, d[1][1], 0, 0, 0);
    }
  }
}

__global__ void __launch_bounds__(256) __attribute__((amdgpu_waves_per_eu(4)))
dqc_main(const float* __restrict__ x,
         const float* __restrict__ pre_w,
         const float* __restrict__ pre_b,
         const float* __restrict__ post_w,
         const float* __restrict__ post_b,
         const u32* __restrict__ Bbuf,
         float* __restrict__ out)
{
  const int lane = threadIdx.x & 63;
  const bool hi  = lane >= 32;
  const int b    = blockIdx.x * 4 + (threadIdx.x >> 6);
  const int axor = (lane ^ 32) << 2;
  // flip-partner masks: class k flips lower f16 when k ^ hi == 1.
  const u32 maskA = hi ? 0x0000FFFFu : 0xFFFF0000u;   // parity-class 0
  const u32 maskB = ~maskA;                            // parity-class 1

  // ---- pre-GEMM: pre[w] = x[b,:] . pre_w[w,:]
  float acc[NQ];
  const float* xr = x + (size_t)b * DIN + lane * 8;
  const float4 xa = *(const float4*)(xr);
  const float4 xb = *(const float4*)(xr + 4);
  #pragma unroll
  for (int w = 0; w < NQ; ++w) {
    const float* wr = pre_w + w * DIN + lane * 8;
    const float4 wa = *(const float4*)(wr);
    const float4 wb = *(const float4*)(wr + 4);
    acc[w] = xa.x * wa.x + xa.y * wa.y + xa.z * wa.z + xa.w * wa.w
           + xb.x * wb.x + xb.y * wb.y + xb.z * wb.z + xb.w * wb.w;
  }
  #pragma unroll
  for (int w = 0; w < NQ; ++w) acc[w] = wave_sum(acc[w]);

  const float PI_4 = 0.78539816339744830962f;
  const float INV_SQRT2 = 0.70710678118654752440f;
  float v0[NQ], v1[NQ];
  #pragma unroll
  for (int w = 0; w < NQ; ++w) {
    float h = (acc[w] + pre_b[w]) * PI_4;
    float s, c;
    sincosf(h, &s, &c);
    v0[w] = (c - s) * INV_SQRT2;
    v1[w] = (c + s) * INV_SQRT2;
  }

  // ---- initial product state, built directly as MM0 A-frags:
  // A[m=q][k=p], q = 32*mt + (lane&31), p = 16*kt + 8*hi + j
  float base8[8];
  #pragma unroll
  for (int j = 0; j < 8; ++j)
    base8[j] = ((j & 1) ? v1[0] : v0[0]) * ((j & 2) ? v1[1] : v0[1]) * ((j & 4) ? v1[2] : v0[2]);
  float hiP[4];
  #pragma unroll
  for (int kt = 0; kt < 4; ++kt)
    hiP[kt] = (hi ? v1[3] : v0[3]) * ((kt & 1) ? v1[4] : v0[4]) * ((kt & 2) ? v1[5] : v0[5]);
  const float qb = ((lane & 1) ? v1[6] : v0[6]) * ((lane & 2) ? v1[7] : v0[7])
                 * ((lane & 4) ? v1[8] : v0[8]) * ((lane & 8) ? v1[9] : v0[9])
                 * ((lane & 16) ? v1[10] : v0[10]);
  const float qm0 = qb * v0[11], qm1 = qb * v1[11];

  f32x16 d[2][2];
  {
    const u32* Bl = Bbuf + lane * 4;   // mm = 0
    #pragma unroll
    for (int kt = 0; kt < 4; ++kt) {
      u32 a0[4], a1[4];
      #pragma unroll
      for (int dw = 0; dw < 4; ++dw) {
        const float e0 = base8[2 * dw] * hiP[kt];
        const float e1 = base8[2 * dw + 1] * hiP[kt];
        a0[dw] = pkrtz(qm0 * e0, qm0 * e1);
        a1[dw] = pkrtz(qm1 * e0, qm1 * e1);
      }
      f16x8 A0 = asf(a0), A1 = asf(a1);
      f16x8 B0 = ldB(Bl, (0 * 4 + kt) * 256);
      f16x8 B1 = ldB(Bl, (1 * 4 + kt) * 256);
      if (kt == 0) {
        f32x16 z{};
        d[0][0] = __builtin_amdgcn_mfma_f32_32x32x16_f16(A0, B0, z, 0, 0, 0);
        d[0][1] = __builtin_amdgcn_mfma_f32_32x32x16_f16(A0, B1, z, 0, 0, 0);
        d[1][0] = __builtin_amdgcn_mfma_f32_32x32x16_f16(A1, B0, z, 0, 0, 0);
        d[1][1] = __builtin_amdgcn_mfma_f32_32x32x16_f16(A1, B1, z, 0, 0, 0);
      } else {
        d[0][0] = __builtin_amdgcn_mfma_f32_32x32x16_f16(A0, B0, d[0][0], 0, 0, 0);
        d[0][1] = __builtin_amdgcn_mfma_f32_32x32x16_f16(A0, B1, d[0][1], 0, 0, 0);
        d[1][0] = __builtin_amdgcn_mfma_f32_32x32x16_f16(A1, B0, d[1][0], 0, 0, 0);
        d[1][1] = __builtin_amdgcn_mfma_f32_32x32x16_f16(A1, B1, d[1][1], 0, 0, 0);
      }
    }
  }

  // ---- MM 1..11. Flip after odd (Q-side) step t is folded into step t+1's
  // repack (FOLD=true on even t); the final flip (after t=11) is folded into
  // the measurement sign algebra below.
  #pragma clang loop unroll(disable)
  for (int i = 0; i < 5; ++i) {
    mm_step<false>(d, Bbuf + (2 * i + 1) * 2048 + lane * 4, hi, axor, maskA, maskB);
    mm_step<true >(d, Bbuf + (2 * i + 2) * 2048 + lane * 4, hi, axor, maskA, maskB);
  }
  mm_step<false>(d, Bbuf + 11 * 2048 + lane * 4, hi, axor, maskA, maskB);

  // ---- measurement. State needs one more cond-flip (lane-xor-1 when
  // par0(r,mt)^hi == 1). Instead of moving data: split sums by parity class
  // (A0/A1, s00/s01). Flipped-class elements contribute with negated
  // lane-bit0 sign; all q'-side masks contain bit0, so:
  //   z[6+j] = s_j(lane) * sgnhi * (A0 - A1)
  //   z[11]  = s_5(lane) * sgnhi * (2*(s00 - s01) - (A0 - A1))
  float A0 = 0.f, A1 = 0.f, s00 = 0.f, s01 = 0.f;
  float zp0 = 0.f, zp1 = 0.f, zp3 = 0.f, zp4 = 0.f, zp5 = 0.f;
  #pragma unroll
  for (int mt = 0; mt < 2; ++mt)
    #pragma unroll
    for (int nt = 0; nt < 2; ++nt)
      #pragma unroll
      for (int r = 0; r < 16; ++r) {
        float v = d[mt][nt][r];
        float sq = v * v;
        const int par0 = (__builtin_popcount(r & 3) + __builtin_popcount(r >> 2) + mt) & 1;
        if (par0) A1 += sq; else A0 += sq;
        if (nt == 0) { if (par0) s01 += sq; else s00 += sq; }
        const int c0 = r & 1;
        const int c1 = (r ^ (r >> 1)) & 1;
        const int c3 = c1 ^ ((r >> 2) & 1);
        const int c4 = c3 ^ ((r >> 3) & 1);
        const int c5 = c4 ^ mt;
        zp0 += c0 ? -sq : sq;
        zp1 += c1 ? -sq : sq;
        zp3 += c3 ? -sq : sq;
        zp4 += c4 ? -sq : sq;
        zp5 += c5 ? -sq : sq;
      }
  const float sgnhi = hi ? -1.f : 1.f;   // p2 = l5 enters wires >= 2
  const float tot   = A0 + A1;
  const float diff  = sgnhi * (A0 - A1);           // flip-corrected q' total
  const float diffs = sgnhi * (2.f * (s00 - s01) - (A0 - A1));
  float z[12];
  z[0] = zp0;
  z[1] = zp1;
  z[2] = sgnhi * zp1;   // reg-part of wire2 mask == wire1 mask
  z[3] = sgnhi * zp3;
  z[4] = sgnhi * zp4;
  z[5] = sgnhi * zp5;
  #pragma unroll
  for (int j = 0; j < 5; ++j) {
    const int par = __builtin_popcount(lane & ((2 << j) - 1)) & 1;
    z[6 + j] = par ? -diff : diff;
  }
  {
    const int par = __builtin_popcount(lane & 31) & 1;  // q'5 = nt via s0 split
    z[11] = par ? -diffs : diffs;
  }
  const float tots = wave_sum(tot);
  #pragma unroll
  for (int w = 0; w < 12; ++w) z[w] = wave_sum(z[w]);

  if (lane == 0) {
    const float inv = 1.0f / tots;
    float o = post_b[0];
    #pragma unroll
    for (int w = 0; w < 12; ++w) o = fmaf(z[w] * inv, post_w[w], o);
    out[b] = o;
  }
}

extern "C" void kernel_launch(void* const* d_in, const int* in_sizes, int n_in,
                              void* d_out, int out_size, void* d_ws, size_t ws_size,
                              hipStream_t stream) {
  (void)in_sizes; (void)n_in; (void)out_size; (void)ws_size;
  const float* x       = (const float*)d_in[0];
  const float* pre_w   = (const float*)d_in[1];
  const float* pre_b   = (const float*)d_in[2];
  const float* weights = (const float*)d_in[3];
  const float* post_w  = (const float*)d_in[4];
  const float* post_b  = (const float*)d_in[5];
  float* out = (float*)d_out;
  u32* Bbuf = (u32*)d_ws;   // 12 * 2048 dwords = 96 KiB

  setup_mats<<<96, 256, 0, stream>>>(weights, Bbuf);
  dqc_main<<<BATCHN / 4, 256, 0, stream>>>(x, pre_w, pre_b, post_w, post_b, Bbuf, out);
}